// Round 3
// baseline (691.102 us; speedup 1.0000x reference)
//
#include <hip/hip_runtime.h>

typedef __bf16 bf16x8 __attribute__((ext_vector_type(8)));
typedef float f32x4 __attribute__((ext_vector_type(4)));
typedef unsigned short ushort8 __attribute__((ext_vector_type(8)));
typedef unsigned int uu2 __attribute__((ext_vector_type(2)));

#define LDS_AS(p) ((__attribute__((address_space(3))) void*)(p))
#define GLB_AS(p) ((const __attribute__((address_space(1))) void*)(p))

__device__ __forceinline__ unsigned short f2bf(float f) {
    union { float f; unsigned u; } v; v.f = f;
    unsigned r = v.u + 0x7fffu + ((v.u >> 16) & 1u);
    return (unsigned short)(r >> 16);
}

// ---------------- weight conversion + vt pad-zero ----------------
// vt is [NWIN*12*32 rows][64] bf16; rows l in [49,64) must be zero so the
// PV MFMA's padded k-lanes multiply P(=0 exactly) by a finite value.
__global__ __launch_bounds__(256) void convw_kernel(
    const float* __restrict__ wi, const float* __restrict__ wo,
    unsigned short* __restrict__ qw, unsigned short* __restrict__ ow,
    unsigned short* __restrict__ vt)
{
    const int i = blockIdx.x * 256 + threadIdx.x;
    if (i < 1152 * 384) qw[i] = f2bf(wi[i]);
    if (i < 384 * 384)  ow[i] = f2bf(wo[i]);
    if (i < 786432) {   // 2048*12*32 vt rows
        unsigned short* p = vt + (size_t)i * 64;
#pragma unroll
        for (int c = 49; c < 64; ++c) p[c] = 0;
    }
}

// ---------------- LayerNorm + window partition + bf16 cast ----------------
__global__ __launch_bounds__(256) void ln_kernel(
    const float* __restrict__ x, const float* __restrict__ gam,
    const float* __restrict__ bet, unsigned short* __restrict__ y)
{
    const int lane = threadIdx.x & 63;
    const int wv   = threadIdx.x >> 6;
    const int m    = blockIdx.x * 4 + wv;
    const int win  = m / 49, l = m - win * 49;
    const int b = win >> 6, wh = (win >> 3) & 7, ww = win & 7;
    const int i = l / 7, j = l - i * 7;
    const float2* xr = (const float2*)(x + ((size_t)b * 3136 + (wh * 7 + i) * 56 + (ww * 7 + j)) * 384);

    float2 v[3];
    float s = 0.f, ss = 0.f;
#pragma unroll
    for (int t = 0; t < 3; ++t) {
        v[t] = xr[t * 64 + lane];
        s  += v[t].x + v[t].y;
        ss += v[t].x * v[t].x + v[t].y * v[t].y;
    }
#pragma unroll
    for (int d = 1; d < 64; d <<= 1) {
        s  += __shfl_xor(s, d, 64);
        ss += __shfl_xor(ss, d, 64);
    }
    const float mu  = s * (1.f / 384.f);
    const float var = ss * (1.f / 384.f) - mu * mu;
    const float rs  = rsqrtf(var + 1e-5f);

    unsigned* yr = (unsigned*)(y + (size_t)m * 384);
#pragma unroll
    for (int t = 0; t < 3; ++t) {
        const int c = (t * 64 + lane) * 2;
        float a0 = (v[t].x - mu) * rs * gam[c]     + bet[c];
        float a1 = (v[t].y - mu) * rs * gam[c + 1] + bet[c + 1];
        yr[t * 64 + lane] = (unsigned)f2bf(a0) | ((unsigned)f2bf(a1) << 16);
    }
}

// ---------------- 256x128 bf16 MFMA GEMM, K=384, BK=32, 8 waves ----------------
// R3: bigger tile = 2x MFMA per barrier (the 2-phase convoy cost is quasi-fixed
//     per step), 72 KB LDS -> 2 blocks/CU = 16 waves/CU (was ~9).
// EPI=0 (qkv): cols <768 (Q,K) -> packed [m][768] bf16 store; cols >=768 (V)
//     -> transposed scalar store into vt[(win*12+h)*32+c][l] so attention
//     reads V fragments with b128 instead of a 32-instr scalar gather.
// EPI=1 (out): window-reverse + residual + fp32 store.
template <int N_, int EPI>
__global__ __launch_bounds__(512, 4) void gemm_kernel(
    const unsigned short* __restrict__ A,
    const unsigned short* __restrict__ Bw,
    const float* __restrict__ bias,
    unsigned short* __restrict__ obf,
    unsigned short* __restrict__ vt,
    const float* __restrict__ xres,
    float* __restrict__ oflt)
{
    __shared__ unsigned short As[3][256 * 32];
    __shared__ unsigned short Bs[3][128 * 32];
    const int lane = threadIdx.x & 63;
    const int wv   = threadIdx.x >> 6;      // 0..7

    // XCD-chunked swizzle (grid % 8 == 0), n varies fastest
    const int NB = N_ / 128;
    int sw = blockIdx.x;
    if ((gridDim.x & 7) == 0)
        sw = (sw & 7) * (int)(gridDim.x >> 3) + (sw >> 3);
    const int my = sw / NB;
    const int m0 = my * 256;
    const int n0 = (sw - my * NB) * 128;

    const int wm = (wv & 3) * 64;           // 4 wave-rows
    const int wn = (wv >> 2) * 64;          // 2 wave-cols
    const int cl = lane & 15;
    const int qd = lane >> 4;
    const int srow = lane >> 2;                                  // 0..15
    const int scol = ((lane & 3) ^ ((lane >> 3) & 3)) * 8;       // swizzled source chunk
    const int rc   = (qd ^ ((cl >> 1) & 3)) * 8;                 // swizzled read chunk

    const unsigned short* gA = A  + (size_t)(m0 + wv * 32 + srow) * 384 + scol;
    const unsigned short* gB = Bw + (size_t)(n0 + wv * 16 + srow) * 384 + scol;

    f32x4 acc[4][4] = {};

#define STAGE(BUF, KB) do {                                                                                        \
    __builtin_amdgcn_global_load_lds(GLB_AS(gA + (KB) * 32),            LDS_AS(&As[BUF][(wv * 32) * 32]),      16, 0, 0); \
    __builtin_amdgcn_global_load_lds(GLB_AS(gA + 16 * 384 + (KB) * 32), LDS_AS(&As[BUF][(wv * 32 + 16) * 32]), 16, 0, 0); \
    __builtin_amdgcn_global_load_lds(GLB_AS(gB + (KB) * 32),            LDS_AS(&Bs[BUF][(wv * 16) * 32]),      16, 0, 0); \
  } while (0)

    STAGE(0, 0);
    STAGE(1, 1);

#pragma unroll
    for (int kb = 0; kb < 12; ++kb) {
        const int cur = kb % 3;
        // wait for own tile-kb loads (3/wave may stay in flight), then barrier
        // => all waves' tile-kb loads complete. Never drain to 0 mid-loop.
        if (kb < 11) asm volatile("s_waitcnt vmcnt(3)\n\ts_barrier" ::: "memory");
        else         asm volatile("s_waitcnt vmcnt(0)\n\ts_barrier" ::: "memory");

        if (kb < 10) STAGE((kb + 2) % 3, kb + 2);

        bf16x8 af[4], bfr[4];
#pragma unroll
        for (int mt = 0; mt < 4; ++mt)
            af[mt] = *(const bf16x8*)(&As[cur][(wm + mt * 16 + cl) * 32 + rc]);
#pragma unroll
        for (int nt = 0; nt < 4; ++nt)
            bfr[nt] = *(const bf16x8*)(&Bs[cur][(wn + nt * 16 + cl) * 32 + rc]);
#pragma unroll
        for (int mt = 0; mt < 4; ++mt)
#pragma unroll
            for (int nt = 0; nt < 4; ++nt)   // swapped operands: lane cl -> m, qd*4+r -> n
                acc[mt][nt] = __builtin_amdgcn_mfma_f32_16x16x32_bf16(bfr[nt], af[mt], acc[mt][nt], 0, 0, 0);
    }
#undef STAGE

#pragma unroll
    for (int mt = 0; mt < 4; ++mt) {
        const int m = m0 + wm + mt * 16 + cl;
        const int win = m / 49, l = m - win * 49;
        size_t rowbase = 0;
        if (EPI == 1) {
            const int b = win >> 6, wh = (win >> 3) & 7, ww = win & 7;
            const int i = l / 7, j = l - i * 7;
            rowbase = ((size_t)b * 3136 + (wh * 7 + i) * 56 + (ww * 7 + j)) * 384;
        }
#pragma unroll
        for (int nt = 0; nt < 4; ++nt) {
            const int nb = n0 + wn + nt * 16 + qd * 4;
            const f32x4 bv = *(const f32x4*)(bias + nb);
            if (EPI == 0) {
                if (n0 < 768) {        // Q,K -> packed [m][768]
                    uu2 p;
                    p[0] = (unsigned)f2bf(acc[mt][nt][0] + bv[0]) |
                           ((unsigned)f2bf(acc[mt][nt][1] + bv[1]) << 16);
                    p[1] = (unsigned)f2bf(acc[mt][nt][2] + bv[2]) |
                           ((unsigned)f2bf(acc[mt][nt][3] + bv[3]) << 16);
                    *(uu2*)(obf + (size_t)m * 768 + nb) = p;
                } else {               // V -> transposed vt[(win*12+h)*32+c][l]
                    const int cf = nb - 768;
                    const int h = cf >> 5, c0 = cf & 31;
                    unsigned short* vp = vt + ((size_t)(win * 12 + h) * 32 + c0) * 64 + l;
#pragma unroll
                    for (int r = 0; r < 4; ++r)
                        vp[r * 64] = f2bf(acc[mt][nt][r] + bv[r]);
                }
            } else {
                const f32x4 xr = *(const f32x4*)(xres + rowbase + nb);
                f32x4 o;
#pragma unroll
                for (int r = 0; r < 4; ++r) o[r] = acc[mt][nt][r] + bv[r] + xr[r];
                *(f32x4*)(oflt + rowbase + nb) = o;
            }
        }
    }
}

// ---------------- attention: one wave per (window, head) ----------------
// qkv is packed [m][768] (Q at 0, K at 384); V comes pre-transposed from vt.
__global__ __launch_bounds__(256) void attn_kernel(
    const unsigned short* __restrict__ qkv,
    const unsigned short* __restrict__ vt,
    unsigned short* __restrict__ o)
{
    __shared__ unsigned short P[4][64 * 72];   // per-wave, stride 72
    const int lane = threadIdx.x & 63;
    const int wv   = threadIdx.x >> 6;
    const int cl = lane & 15;
    const int qd = lane >> 4;
    const int g   = blockIdx.x * 4 + wv;
    const int win = g / 12;
    const int h   = g - win * 12;
    const unsigned short* base = qkv + (size_t)win * (49 * 768);

    // S = Q @ K^T  (64x64 padded, K=32)
    bf16x8 aq[4], bk[4];
#pragma unroll
    for (int mt = 0; mt < 4; ++mt) {
        const int l = mt * 16 + cl;
        bf16x8 z = {};
        if (l < 49) z = *(const bf16x8*)(base + (size_t)l * 768 + h * 32 + qd * 8);
        aq[mt] = z;
    }
#pragma unroll
    for (int nt = 0; nt < 4; ++nt) {
        const int lk = nt * 16 + cl;
        bf16x8 z = {};
        if (lk < 49) z = *(const bf16x8*)(base + (size_t)lk * 768 + 384 + h * 32 + qd * 8);
        bk[nt] = z;
    }
    f32x4 s[4][4] = {};
#pragma unroll
    for (int mt = 0; mt < 4; ++mt)
#pragma unroll
        for (int nt = 0; nt < 4; ++nt)
            s[mt][nt] = __builtin_amdgcn_mfma_f32_16x16x32_bf16(aq[mt], bk[nt], s[mt][nt], 0, 0, 0);

    const float scale = 0.17677669529663687f;   // 1/sqrt(32)
#pragma unroll
    for (int mt = 0; mt < 4; ++mt)
#pragma unroll
        for (int nt = 0; nt < 4; ++nt)
#pragma unroll
            for (int r = 0; r < 4; ++r) {
                float t = s[mt][nt][r] * scale;
                if (nt * 16 + cl >= 49) t = -1e30f;
                s[mt][nt][r] = t;
            }

    // softmax over rows
#pragma unroll
    for (int mt = 0; mt < 4; ++mt)
#pragma unroll
        for (int r = 0; r < 4; ++r) {
            float mx = fmaxf(fmaxf(s[mt][0][r], s[mt][1][r]), fmaxf(s[mt][2][r], s[mt][3][r]));
            mx = fmaxf(mx, __shfl_xor(mx, 1, 64));
            mx = fmaxf(mx, __shfl_xor(mx, 2, 64));
            mx = fmaxf(mx, __shfl_xor(mx, 4, 64));
            mx = fmaxf(mx, __shfl_xor(mx, 8, 64));
            float sm = 0.f;
#pragma unroll
            for (int nt = 0; nt < 4; ++nt) {
                const float p = __expf(s[mt][nt][r] - mx);
                s[mt][nt][r] = p;
                sm += p;
            }
            sm += __shfl_xor(sm, 1, 64);
            sm += __shfl_xor(sm, 2, 64);
            sm += __shfl_xor(sm, 4, 64);
            sm += __shfl_xor(sm, 8, 64);
            const float inv = 1.f / sm;
#pragma unroll
            for (int nt = 0; nt < 4; ++nt)
                s[mt][nt][r] *= inv;
        }

    // P -> LDS (C-layout scatter), read back in A-layout. P[q][k>=49] == 0.
    unsigned short* Pw = &P[wv][0];
#pragma unroll
    for (int mt = 0; mt < 4; ++mt)
#pragma unroll
        for (int nt = 0; nt < 4; ++nt)
#pragma unroll
            for (int r = 0; r < 4; ++r)
                Pw[(mt * 16 + qd * 4 + r) * 72 + nt * 16 + cl] = f2bf(s[mt][nt][r]);

    // O = P @ V   (64x32, K=64); V fragments straight from vt (b128 loads)
    f32x4 oa[4][2] = {};
    const unsigned short* vtb = vt + (size_t)(win * 12 + h) * 2048;
#pragma unroll
    for (int kk = 0; kk < 2; ++kk) {
        bf16x8 ap[4];
#pragma unroll
        for (int mt = 0; mt < 4; ++mt)
            ap[mt] = *(const bf16x8*)(Pw + (mt * 16 + cl) * 72 + kk * 32 + qd * 8);
#pragma unroll
        for (int nt = 0; nt < 2; ++nt) {
            const bf16x8 bv = *(const bf16x8*)(vtb + (size_t)(nt * 16 + cl) * 64 + kk * 32 + qd * 8);
#pragma unroll
            for (int mt = 0; mt < 4; ++mt)
                oa[mt][nt] = __builtin_amdgcn_mfma_f32_16x16x32_bf16(ap[mt], bv, oa[mt][nt], 0, 0, 0);
        }
    }

    unsigned short* ob = o + (size_t)win * 49 * 384 + h * 32;
#pragma unroll
    for (int mt = 0; mt < 4; ++mt)
#pragma unroll
        for (int r = 0; r < 4; ++r) {
            const int l = mt * 16 + qd * 4 + r;
            if (l < 49) {
#pragma unroll
                for (int nt = 0; nt < 2; ++nt)
                    ob[(size_t)l * 384 + nt * 16 + cl] = f2bf(oa[mt][nt][r]);
            }
        }
}

extern "C" void kernel_launch(void* const* d_in, const int* in_sizes, int n_in,
                              void* d_out, int out_size, void* d_ws, size_t ws_size,
                              hipStream_t stream)
{
    const float* x   = (const float*)d_in[0];
    const float* gam = (const float*)d_in[1];
    const float* bet = (const float*)d_in[2];
    const float* wi  = (const float*)d_in[3];
    const float* bi  = (const float*)d_in[4];
    const float* wo  = (const float*)d_in[5];
    const float* bo  = (const float*)d_in[6];
    float* out = (float*)d_out;

    const int Bb   = in_sizes[0] / (3136 * 384);  // 32
    const int M    = Bb * 3136;                   // 100352 (= NWIN*49)
    const int NWIN = Bb * 64;

    char* ws = (char*)d_ws;
    unsigned short* qw   = (unsigned short*)(ws);                       // w_in bf16 (884736 B)
    unsigned short* ow   = (unsigned short*)(ws + 884736);              // w_out bf16 (294912 B)
    unsigned short* y    = (unsigned short*)(ws + 1179648);             // [M,384] bf16 (77 MB)
    unsigned short* qkv  = (unsigned short*)(ws + 1179648 + (size_t)M * 768);            // [M,768] Q,K packed (154 MB)
    unsigned short* vt   = (unsigned short*)(ws + 1179648 + (size_t)M * 768 + (size_t)M * 1536); // [NWIN*12*32][64] (100 MB)
    unsigned short* owin = y;   // y is dead after gemm1; reuse for attn output

    convw_kernel<<<3072, 256, 0, stream>>>(wi, wo, qw, ow, vt);
    ln_kernel<<<M / 4, 256, 0, stream>>>(x, gam, bet, y);
    gemm_kernel<1152, 0><<<(M / 256) * 9, 512, 0, stream>>>(y, qw, bi, qkv, vt, nullptr, nullptr);
    attn_kernel<<<NWIN * 12 / 4, 256, 0, stream>>>(qkv, vt, owin);
    gemm_kernel<384, 1><<<(M / 256) * 3, 512, 0, stream>>>(owin, ow, bo, nullptr, nullptr, x, out);
}